// Round 6
// baseline (151.279 us; speedup 1.0000x reference)
//
#include <hip/hip_runtime.h>
#include <hip/hip_bf16.h>
#include <math.h>

// Problem constants
#define T_SEQ 4096
#define DIM   1024
#define NH    8
#define HDIM  64
#define ETA   4
#define NR    7
#define NKQVC 2688   // combined: 2560 kqv + 96 p + 32 pad
#define CHUNK 16
#define NCHUNK 256   // T_SEQ / CHUNK

typedef __attribute__((ext_vector_type(8))) short bf16x8;
typedef __attribute__((ext_vector_type(4))) short short4v;
typedef __attribute__((ext_vector_type(4))) float f32x4;

// Workspace layout (float offsets). Total 12,618,496 fl = 50.5 MB.
// Permanent:
#define KQVC_OFF    0ul          // combined kqv+p bf16: 4096*2688 sh = 5,505,024 fl
#define OCC_OFF     5505024ul    // occ f32: 4096*8 = 32,768 fl
#define BTPROJ_OFF  5537792ul    // W_proj^T bf16: 1024*512 sh = 262,144 fl
#define ATTNBF_OFF  5799936ul    // attn bf16: 4096*512 sh = 1,048,576 fl
#define BIASC_OFF   6848512ul    // concat bias f32: 2,816 fl
// Transient A (dead after input GEMM):
#define ABF_OFF     6851328ul    // inputs bf16: 2,097,152 fl
#define BTCAT_OFF   8948480ul    // [2688][1024] bf16 = 1,376,256 fl
// Transient B (overlays transient A after GEMM; carry in-place):
#define YSUM_OFF    6851328ul    // 256*8*44*64 = 5,767,168 fl

// Output layout (float offsets), concatenated in return order
#define O_ATTN 0ul
#define O_FK   4194304ul   // (7,8,256)
#define O_FV   4208640ul   // (7,8,64)
#define O_FS   4212224ul   // (8,256)
#define O_TICK 4214272ul   // (1,)

__device__ __forceinline__ float sigm(float x) { return 1.f / (1.f + __expf(-x)); }

__device__ __forceinline__ short f2bf(float f) {
  union { __hip_bfloat16 b; short s; } u;
  u.b = __float2bfloat16(f);
  return u.s;
}
__device__ __forceinline__ float bf2f(short s) {
  union { __hip_bfloat16 b; short s2; } u;
  u.s2 = s;
  return __bfloat162float(u.b);
}

__device__ __forceinline__ void gload16(const void* g, void* l) {
  __builtin_amdgcn_global_load_lds(
      (const __attribute__((address_space(1))) void*)g,
      (__attribute__((address_space(3))) void*)l, 16, 0, 0);
}

// ---------------------------------------------------------------------------
// Cast f32 -> bf16, 4 elements/thread.
// ---------------------------------------------------------------------------
__global__ __launch_bounds__(256) void cast_f32_bf16(
    const float* __restrict__ x, short* __restrict__ y) {
  size_t i = (size_t)(blockIdx.x * 256 + threadIdx.x) * 4;
  float4 v = *(const float4*)(x + i);
  short4v o;
  o.x = f2bf(v.x); o.y = f2bf(v.y); o.z = f2bf(v.z); o.w = f2bf(v.w);
  *(short4v*)(y + i) = o;
}

// ---------------------------------------------------------------------------
// Transposing cast: W [K][N] f32 -> Bt [N][K] bf16. 32x32 tiles, block (32,8).
// ---------------------------------------------------------------------------
__global__ __launch_bounds__(256) void transpose_cast(
    const float* __restrict__ W, short* __restrict__ Bt, int K, int N) {
  __shared__ float tile[32][33];
  int n0 = blockIdx.x * 32, k0 = blockIdx.y * 32;
  int tx = threadIdx.x, ty = threadIdx.y;
  for (int i = ty; i < 32; i += 8)
    tile[i][tx] = W[(size_t)(k0 + i) * N + n0 + tx];
  __syncthreads();
  for (int i = ty; i < 32; i += 8)
    Bt[(size_t)(n0 + i) * K + k0 + tx] = f2bf(tile[tx][i]);
}

// ---------------------------------------------------------------------------
// bias_cat = [b_kqv (2560) | b_p (96) | zeros (32)]
// ---------------------------------------------------------------------------
__global__ __launch_bounds__(256) void concat_bias(
    const float* __restrict__ b_kqv, const float* __restrict__ b_p,
    float* __restrict__ bc) {
  int i = blockIdx.x * 256 + threadIdx.x;
  if (i >= NKQVC) return;
  bc[i] = (i < 2560) ? b_kqv[i] : (i < 2656 ? b_p[i - 2560] : 0.f);
}

// ---------------------------------------------------------------------------
// MFMA GEMM: C[M,N] = A[M,K] @ Bt[N,K]^T + bias.  A,Bt bf16.
// 128x128 tile, BK=32, 256 threads (4 waves 2x2), 16x16x32 MFMA.
// Double-buffered LDS staging, ONE barrier per K-step.
// ---------------------------------------------------------------------------
template <int OUT_BF16>
__global__ __launch_bounds__(256) void gemm_bt_mfma(
    const short* __restrict__ A, const short* __restrict__ Bt,
    const float* __restrict__ bias, void* __restrict__ Cout,
    int M, int N, int K) {
  __shared__ __align__(16) short lds[16384];

  // XCD-aware bijective swizzle
  int nwg = gridDim.x;
  int cpx = nwg >> 3;
  int bid = blockIdx.x;
  int swz = (bid & 7) * cpx + (bid >> 3);
  int nbx = N >> 7;
  int bm0 = (swz / nbx) << 7;
  int bn0 = (swz % nbx) << 7;

  const int tid = threadIdx.x;
  const int w = tid >> 6, l = tid & 63;
  const int wm = w >> 1, wn = w & 1;
  const int fr = l & 15;
  const int fq = l >> 4;

  const int ca = w * 2;
  const short* Ag0 = A + (size_t)(bm0 + ca * 16 + (l >> 2)) * K + (l & 3) * 8;
  const short* Ag1 = Ag0 + (size_t)16 * K;
  const short* Bg0 = Bt + (size_t)(bn0 + ca * 16 + (l >> 2)) * K + (l & 3) * 8;
  const short* Bg1 = Bg0 + (size_t)16 * K;

  f32x4 acc[4][4];
#pragma unroll
  for (int mi = 0; mi < 4; ++mi)
#pragma unroll
    for (int ni = 0; ni < 4; ++ni)
#pragma unroll
      for (int r = 0; r < 4; ++r) acc[mi][ni][r] = 0.f;

  const int KT = K >> 5;
  int cur = 0;
  {
    short* la = &lds[ca * 512];
    short* lb = &lds[4096 + ca * 512];
    gload16(Ag0, la);
    gload16(Ag1, la + 512);
    gload16(Bg0, lb);
    gload16(Bg1, lb + 512);
  }
  __syncthreads();

  for (int kt = 0; kt < KT; ++kt) {
    if (kt + 1 < KT) {
      int nb = (cur ^ 1) * 8192;
      int ko = (kt + 1) * 32;
      short* la = &lds[nb + ca * 512];
      short* lb = &lds[nb + 4096 + ca * 512];
      gload16(Ag0 + ko, la);
      gload16(Ag1 + ko, la + 512);
      gload16(Bg0 + ko, lb);
      gload16(Bg1 + ko, lb + 512);
    }
    const short* ArP = &lds[cur * 8192 + (wm * 64 + fr) * 32 + fq * 8];
    const short* BrP = &lds[cur * 8192 + 4096 + (wn * 64 + fr) * 32 + fq * 8];
    bf16x8 af[4], bfv[4];
#pragma unroll
    for (int mi = 0; mi < 4; ++mi) af[mi] = *(const bf16x8*)(ArP + mi * 512);
#pragma unroll
    for (int ni = 0; ni < 4; ++ni) bfv[ni] = *(const bf16x8*)(BrP + ni * 512);
#pragma unroll
    for (int mi = 0; mi < 4; ++mi)
#pragma unroll
      for (int ni = 0; ni < 4; ++ni)
        acc[mi][ni] = __builtin_amdgcn_mfma_f32_16x16x32_bf16(
            af[mi], bfv[ni], acc[mi][ni], 0, 0, 0);
    __syncthreads();
    cur ^= 1;
  }

  // C/D layout: col = lane&15, row = (lane>>4)*4 + reg  [m89 verified]
  if (OUT_BF16) {
#pragma unroll
    for (int ni = 0; ni < 4; ++ni) {
      int col = wn * 64 + ni * 16 + fr;
      float bz = bias[bn0 + col];
#pragma unroll
      for (int mi = 0; mi < 4; ++mi) {
        int row = wm * 64 + mi * 16 + fq * 4;
#pragma unroll
        for (int r = 0; r < 4; ++r)
          lds[(row + r) * 128 + col] = f2bf(acc[mi][ni][r] + bz);
      }
    }
    __syncthreads();
    int row = tid >> 1, half = tid & 1;
    const f32x4* src = (const f32x4*)&lds[row * 128 + half * 64];
    f32x4* dst = (f32x4*)((short*)Cout + (size_t)(bm0 + row) * N + bn0 + half * 64);
#pragma unroll
    for (int i = 0; i < 8; ++i) dst[i] = src[i];
  } else {
#pragma unroll
    for (int ni = 0; ni < 4; ++ni) {
      int col = bn0 + wn * 64 + ni * 16 + fr;
      float bz = bias[col];
#pragma unroll
      for (int mi = 0; mi < 4; ++mi) {
        int row = bm0 + wm * 64 + mi * 16 + fq * 4;
#pragma unroll
        for (int r = 0; r < 4; ++r)
          ((float*)Cout)[(size_t)(row + r) * N + col] = acc[mi][ni][r] + bz;
      }
    }
  }
}

// ---------------------------------------------------------------------------
// occil[t][r] = cos((tick + t + 1) * omega_r), omega = linspace(-pi, pi, 7)
// ---------------------------------------------------------------------------
__global__ __launch_bounds__(256) void occil_kernel(const float* __restrict__ tick,
                                                    float* __restrict__ occ) {
  int t = blockIdx.x * 256 + threadIdx.x;
  if (t >= T_SEQ) return;
  float tickt = tick[0] + (float)(t + 1);
#pragma unroll
  for (int r = 0; r < NR; ++r) {
    float om = (float)(-3.14159265358979323846 + r * (3.14159265358979323846 / 3.0));
    occ[t * 8 + r] = cosf(tickt * om);
  }
  occ[t * 8 + 7] = 0.f;
}

// ---------------------------------------------------------------------------
// Pass A (2-wave r-split): block = 128 threads = 2 waves per (chunk, head).
// Wave 0 owns r = 0..3 (+Pb); wave 1 owns r = 4..6 (+ys, Pg).
// Register arrays indexed ONLY by compile-time rr (0..3) with rr<RN guards;
// runtime R0 offset used only for LDS/global addressing (rule #20 safe).
// ysum layout unchanged: [c][h][slot(44)][dd]; slots: fk r*4+n (0..27),
// fv 28+r, fs 35+n, Pg 39+n, Pb 43.
// ---------------------------------------------------------------------------
__global__ __launch_bounds__(128) void pass_a(
    const short* __restrict__ kqv, const float* __restrict__ occ,
    const int* __restrict__ term, float* __restrict__ ysum) {
  const int c = blockIdx.x, h = blockIdx.y;
  const int tid = threadIdx.x;
  const int w = tid >> 6, dd = tid & 63;
  const int R0 = w ? 4 : 0;
  const int RN = w ? 3 : 4;
  __shared__ float sp[CHUNK][12];
  __shared__ float socc[CHUNK][8];
  __shared__ float snt[CHUNK];
  for (int i = tid; i < CHUNK * 12; i += 128) {
    int t = i / 12, j = i - t * 12;
    sp[t][j] = bf2f(kqv[(size_t)(c * CHUNK + t) * NKQVC + 2560 + h * 12 + j]);
  }
  for (int i = tid; i < CHUNK * 8; i += 128)
    socc[i >> 3][i & 7] = occ[(size_t)c * CHUNK * 8 + i];
  for (int t = tid; t < CHUNK; t += 128)
    snt[t] = 1.f - (float)term[c * CHUNK + t];
  __syncthreads();

  float yk[4][ETA], yv[4], ys[ETA], Pg[ETA], Pb = 1.f;
#pragma unroll
  for (int rr = 0; rr < 4; ++rr) {
    yv[rr] = 0.f;
#pragma unroll
    for (int n = 0; n < ETA; ++n) yk[rr][n] = 0.f;
  }
#pragma unroll
  for (int n = 0; n < ETA; ++n) { ys[n] = 0.f; Pg[n] = 1.f; }

  size_t bcur = (size_t)(c * CHUNK) * NKQVC + h * 320 + dd;
  short ck = kqv[bcur], cv = kqv[bcur + 128], cbt = kqv[bcur + 192], cg = kqv[bcur + 256];
  for (int t = 0; t < CHUNK; ++t) {
    size_t bnx = bcur + (t < CHUNK - 1 ? NKQVC : 0);
    short nk = kqv[bnx], nv = kqv[bnx + 128], nbt = kqv[bnx + 192], ng = kqv[bnx + 256];

    float nt = snt[t];
    float rk = fmaxf(bf2f(ck), 0.f);
    float sg = sigm(bf2f(cg));
    float sb = sigm(bf2f(cbt));
    float occr[4];
#pragma unroll
    for (int rr = 0; rr < 4; ++rr) occr[rr] = socc[t][R0 + rr];  // LDS dyn-idx OK
#pragma unroll
    for (int n = 0; n < ETA; ++n) {
      float rp1 = fmaxf(sp[t][n], 0.f);
      float sp3 = sigm(sp[t][8 + n]);
      float gam = sg * sp3;
      float xs  = rk * rp1 * gam;
      float dg  = (1.f - gam) * nt;
      if (w) {
        Pg[n] *= dg;
        ys[n] = fmaf(ys[n], dg, xs);
      }
#pragma unroll
      for (int rr = 0; rr < 4; ++rr)
        if (rr < RN) yk[rr][n] = fmaf(yk[rr][n], dg, xs * occr[rr]);
    }
    float vb = bf2f(cv) * sb;
    float db = (1.f - sb) * nt;
    if (!w) Pb *= db;
#pragma unroll
    for (int rr = 0; rr < 4; ++rr)
      if (rr < RN) yv[rr] = fmaf(yv[rr], db, vb * occr[rr]);

    ck = nk; cv = nv; cbt = nbt; cg = ng; bcur = bnx;
  }

  float* o = ysum + (size_t)(c * NH + h) * 44 * 64 + dd;
#pragma unroll
  for (int rr = 0; rr < 4; ++rr)
    if (rr < RN) {
#pragma unroll
      for (int n = 0; n < ETA; ++n) o[((R0 + rr) * 4 + n) * 64] = yk[rr][n];
      o[(28 + R0 + rr) * 64] = yv[rr];
    }
  if (w) {
#pragma unroll
    for (int n = 0; n < ETA; ++n) o[(35 + n) * 64] = ys[n];
#pragma unroll
    for (int n = 0; n < ETA; ++n) o[(39 + n) * 64] = Pg[n];
  } else {
    o[43 * 64] = Pb;
  }
}

// ---------------------------------------------------------------------------
// Pass B: carry propagation IN-PLACE in ysum; ring-buffer prefetch PD=16.
// ---------------------------------------------------------------------------
__global__ __launch_bounds__(256) void pass_b(
    float* __restrict__ ysum, const float* __restrict__ k_prev,
    const float* __restrict__ v_prev, const float* __restrict__ s_prev) {
  int idx = blockIdx.x * 256 + threadIdx.x;
  int dd = idx & 63;
  int slot = (idx >> 6) % 39;
  int h = idx / (39 * 64);

  int pslot;
  float f;
  if (slot < 28) {
    int r = slot >> 2, n = slot & 3;
    f = k_prev[(size_t)(r * NH + h) * 256 + n * 64 + dd];
    pslot = 39 + n;
  } else if (slot < 35) {
    int r = slot - 28;
    f = v_prev[(size_t)(r * NH + h) * 64 + dd];
    pslot = 43;
  } else {
    int n = slot - 35;
    f = s_prev[(size_t)h * 256 + n * 64 + dd];
    pslot = 39 + n;
  }
  const size_t STRIDE = (size_t)NH * 2816;  // 44*64 per head
  float* yb = ysum + (size_t)h * 2816 + slot * 64 + dd;
  const float* pb = ysum + (size_t)h * 2816 + pslot * 64 + dd;

#define PD 16
  float yring[PD], pring[PD];
#pragma unroll
  for (int d = 0; d < PD; ++d) {
    yring[d] = yb[(size_t)d * STRIDE];
    pring[d] = pb[(size_t)d * STRIDE];
  }
  const int NB = NCHUNK / PD;
  for (int cb = 0; cb < NB; ++cb) {
    int c0 = cb * PD;
    float ynext[PD], pnext[PD];
    if (cb + 1 < NB) {
#pragma unroll
      for (int j = 0; j < PD; ++j) {
        ynext[j] = yb[(size_t)(c0 + PD + j) * STRIDE];
        pnext[j] = pb[(size_t)(c0 + PD + j) * STRIDE];
      }
    }
#pragma unroll
    for (int j = 0; j < PD; ++j) {
      yb[(size_t)(c0 + j) * STRIDE] = f;
      f = fmaf(f, pring[j], yring[j]);
    }
    if (cb + 1 < NB) {
#pragma unroll
      for (int j = 0; j < PD; ++j) { yring[j] = ynext[j]; pring[j] = pnext[j]; }
    }
  }
#undef PD
}

// ---------------------------------------------------------------------------
// Pass C (2-wave r-split): wave 0 owns r=0..3 and writes attn; wave 1 owns
// r=4..6 + fs/norm chain, computes denom and its kvv partial, passes both
// through a parity-double-buffered LDS slot (1 barrier per t — safe: buffer
// [par] is rewritten at t+2 only after the t+1 barrier, which wave 0 reaches
// only after reading [par] at t).
// ---------------------------------------------------------------------------
__global__ __launch_bounds__(128) void pass_c(
    const short* __restrict__ kqv, const float* __restrict__ occ,
    const int* __restrict__ term, const float* __restrict__ carry,
    short* __restrict__ attn, float* __restrict__ out,
    const float* __restrict__ tick) {
  const int c = blockIdx.x, h = blockIdx.y;
  const int tid = threadIdx.x;
  const int w = tid >> 6, dd = tid & 63;
  const int R0 = w ? 4 : 0;
  const int RN = w ? 3 : 4;
  __shared__ float sp[CHUNK][12];
  __shared__ float socc[CHUNK][8];
  __shared__ float snt[CHUNK];
  __shared__ float xch[2][2][64];   // [parity][{kvv1, denom}][dd]
  for (int i = tid; i < CHUNK * 12; i += 128) {
    int t = i / 12, j = i - t * 12;
    sp[t][j] = bf2f(kqv[(size_t)(c * CHUNK + t) * NKQVC + 2560 + h * 12 + j]);
  }
  for (int i = tid; i < CHUNK * 8; i += 128)
    socc[i >> 3][i & 7] = occ[(size_t)c * CHUNK * 8 + i];
  for (int t = tid; t < CHUNK; t += 128)
    snt[t] = 1.f - (float)term[c * CHUNK + t];

  const float* cp = carry + (size_t)(c * NH + h) * 2816 + dd;
  float fk[4][ETA], fv[4], fs[ETA];
#pragma unroll
  for (int rr = 0; rr < 4; ++rr)
    if (rr < RN) {
#pragma unroll
      for (int n = 0; n < ETA; ++n) fk[rr][n] = cp[((R0 + rr) * 4 + n) * 64];
      fv[rr] = cp[(28 + R0 + rr) * 64];
    }
  if (w) {
#pragma unroll
    for (int n = 0; n < ETA; ++n) fs[n] = cp[(35 + n) * 64];
  }
  __syncthreads();

  size_t bcur = (size_t)(c * CHUNK) * NKQVC + h * 320 + dd;
  short ck = kqv[bcur], cq = kqv[bcur + 64], cv = kqv[bcur + 128],
        cbt = kqv[bcur + 192], cg = kqv[bcur + 256];
  for (int t = 0; t < CHUNK; ++t) {
    size_t bnx = bcur + (t < CHUNK - 1 ? NKQVC : 0);
    short nk = kqv[bnx], nq = kqv[bnx + 64], nv = kqv[bnx + 128],
          nbt = kqv[bnx + 192], ng = kqv[bnx + 256];

    float nt = snt[t];
    float rk = fmaxf(bf2f(ck), 0.f);
    float rq = fmaxf(bf2f(cq), 0.f);
    float sg = sigm(bf2f(cg));
    float sb = sigm(bf2f(cbt));
    float occr[4];
#pragma unroll
    for (int rr = 0; rr < 4; ++rr) occr[rr] = socc[t][R0 + rr];
    float kdqp[4] = {0.f, 0.f, 0.f, 0.f};
    float normp = 0.f;
#pragma unroll
    for (int n = 0; n < ETA; ++n) {
      float rp1 = fmaxf(sp[t][n], 0.f);
      float rp2 = fmaxf(sp[t][4 + n], 0.f);
      float sp3 = sigm(sp[t][8 + n]);
      float gam = sg * sp3;
      float xs  = rk * rp1 * gam;
      float dg  = (1.f - gam) * nt;
      float qf  = rq * rp2;
      if (w) {
        fs[n] = fmaf(fs[n], dg, xs);
        normp = fmaf(fs[n], qf, normp);
      }
#pragma unroll
      for (int rr = 0; rr < 4; ++rr)
        if (rr < RN) {
          fk[rr][n] = fmaf(fk[rr][n], dg, xs * occr[rr]);
          kdqp[rr]  = fmaf(fk[rr][n], qf, kdqp[rr]);
        }
    }
    float vb = bf2f(cv) * sb;
    float db = (1.f - sb) * nt;
#pragma unroll
    for (int rr = 0; rr < 4; ++rr)
      if (rr < RN) fv[rr] = fmaf(fv[rr], db, vb * occr[rr]);

    // 4 butterfly sum-reductions per wave (wave1's slot 3 = norm)
    float red[4];
    red[0] = kdqp[0]; red[1] = kdqp[1]; red[2] = kdqp[2];
    red[3] = w ? normp : kdqp[3];
#pragma unroll
    for (int i = 0; i < 4; ++i) {
      float x = red[i];
#pragma unroll
      for (int m = 1; m < 64; m <<= 1) x += __shfl_xor(x, m, 64);
      red[i] = x;
    }
    int par = t & 1;
    if (w) {
      float kvv1 = fv[0] * red[0];
      kvv1 = fmaf(fv[1], red[1], kvv1);
      kvv1 = fmaf(fv[2], red[2], kvv1);
      float denom = fmaf(14.f, red[3], 1e-5f);  // 2*R*norm + eps
      xch[par][0][dd] = kvv1;
      xch[par][1][dd] = denom;
    }
    __syncthreads();
    if (!w) {
      float kvv = fv[0] * red[0];
      kvv = fmaf(fv[1], red[1], kvv);
      kvv = fmaf(fv[2], red[2], kvv);
      kvv = fmaf(fv[3], red[3], kvv);
      kvv += xch[par][0][dd];
      attn[(size_t)(c * CHUNK + t) * 512 + h * 64 + dd] = f2bf(kvv / xch[par][1][dd]);
    }

    ck = nk; cq = nq; cv = nv; cbt = nbt; cg = ng; bcur = bnx;
  }

  if (c == NCHUNK - 1) {
#pragma unroll
    for (int rr = 0; rr < 4; ++rr)
      if (rr < RN) {
#pragma unroll
        for (int n = 0; n < ETA; ++n)
          out[O_FK + (size_t)((R0 + rr) * NH + h) * 256 + n * 64 + dd] = fk[rr][n];
        out[O_FV + (size_t)((R0 + rr) * NH + h) * 64 + dd] = fv[rr];
      }
    if (w) {
#pragma unroll
      for (int n = 0; n < ETA; ++n)
        out[O_FS + (size_t)h * 256 + n * 64 + dd] = fs[n];
    }
    if (!w && h == 0 && dd == 0) out[O_TICK] = tick[0] + (float)T_SEQ;
  }
}

// ---------------------------------------------------------------------------
extern "C" void kernel_launch(void* const* d_in, const int* in_sizes, int n_in,
                              void* d_out, int out_size, void* d_ws, size_t ws_size,
                              hipStream_t stream) {
  const float* inputs = (const float*)d_in[0];
  const int*   term   = (const int*)d_in[1];
  const float* k_prev = (const float*)d_in[2];
  const float* v_prev = (const float*)d_in[3];
  const float* s_prev = (const float*)d_in[4];
  const float* tick   = (const float*)d_in[5];
  const float* W_kqv  = (const float*)d_in[6];
  const float* b_kqv  = (const float*)d_in[7];
  const float* W_p    = (const float*)d_in[8];
  const float* b_p    = (const float*)d_in[9];
  const float* W_proj = (const float*)d_in[10];
  const float* b_proj = (const float*)d_in[11];
  float* out = (float*)d_out;
  float* ws  = (float*)d_ws;

  short* kqvc   = (short*)(ws + KQVC_OFF);
  float* occ    = ws + OCC_OFF;
  short* BtProj = (short*)(ws + BTPROJ_OFF);
  short* attnbf = (short*)(ws + ATTNBF_OFF);
  float* biasc  = ws + BIASC_OFF;
  short* Abf    = (short*)(ws + ABF_OFF);
  short* BtCat  = (short*)(ws + BTCAT_OFF);
  float* ysum   = ws + YSUM_OFF;   // overlays Abf/BtCat after input GEMM

  // 0) casts, weight transposes (bf16), bias concat
  cast_f32_bf16<<<4096, 256, 0, stream>>>(inputs, Abf);
  transpose_cast<<<dim3(80, 32), dim3(32, 8), 0, stream>>>(W_kqv, BtCat, 1024, 2560);
  transpose_cast<<<dim3(3, 32), dim3(32, 8), 0, stream>>>(
      W_p, BtCat + (size_t)2560 * 1024, 1024, 96);
  transpose_cast<<<dim3(32, 16), dim3(32, 8), 0, stream>>>(W_proj, BtProj, 512, 1024);
  concat_bias<<<11, 256, 0, stream>>>(b_kqv, b_p, biasc);

  // 1) oscillation table
  occil_kernel<<<16, 256, 0, stream>>>(tick, occ);

  // 2) combined kqv+p projection (MFMA, bf16 out): N = 2688
  gemm_bt_mfma<1><<<672, 256, 0, stream>>>(Abf, BtCat, biasc, kqvc,
                                           T_SEQ, NKQVC, DIM);

  // 3) chunked linear scan (2-wave r-split blocks)
  pass_a<<<dim3(NCHUNK, NH), 128, 0, stream>>>(kqvc, occ, term, ysum);
  pass_b<<<78, 256, 0, stream>>>(ysum, k_prev, v_prev, s_prev);
  pass_c<<<dim3(NCHUNK, NH), 128, 0, stream>>>(kqvc, occ, term, ysum,
                                               attnbf, out, tick);

  // 4) output projection (MFMA, f32 out)
  gemm_bt_mfma<0><<<256, 256, 0, stream>>>(attnbf, BtProj, b_proj, out,
                                           T_SEQ, DIM, NH * HDIM);
}